// Round 6
// baseline (140.506 us; speedup 1.0000x reference)
//
#include <hip/hip_runtime.h>
#include <hip/hip_bf16.h>
#include <math.h>

#define S_LEN 2048
#define E_DIM 1024
#define NHEAD 8
#define DH 128
#define E3 3072

typedef short bf16x8 __attribute__((ext_vector_type(8)));
typedef short bf16x4 __attribute__((ext_vector_type(4)));
typedef float f32x4 __attribute__((ext_vector_type(4)));

#define MFMA32(a,b,c) __builtin_amdgcn_mfma_f32_16x16x32_bf16(a,b,c,0,0,0)

__device__ __forceinline__ unsigned short f2bf(float f){
  union{float f; unsigned u;} x; x.f = f;
  unsigned r = x.u + 0x7FFF + ((x.u>>16)&1);
  return (unsigned short)(r>>16);
}

__device__ __forceinline__ unsigned cvtpk(float lo, float hi){
  unsigned r;
  asm("v_cvt_pk_bf16_f32 %0, %1, %2" : "=v"(r) : "v"(lo), "v"(hi));
  return r;
}

__device__ __forceinline__ float logsigf(float x){
  return fminf(x, 0.f) - log1pf(expf(-fabsf(x)));
}

typedef const __attribute__((address_space(1))) unsigned int* gas1_t;
typedef __attribute__((address_space(3))) unsigned int* las3_t;
__device__ __forceinline__ void stage16(const ushort* g, ushort* l){
  __builtin_amdgcn_global_load_lds((gas1_t)(const void*)g, (las3_t)(void*)l, 16, 0, 0);
}

// ---------------- Kernel A: gates + q/k bf16 conversion (fused) ------------
__global__ __launch_bounds__(256) void gates_qk(
    const float* __restrict__ q, const float* __restrict__ k, const float* __restrict__ v,
    const float* __restrict__ igw, const float* __restrict__ igb,
    const float* __restrict__ fgw, const float* __restrict__ fgb,
    float* __restrict__ ig_out, float* __restrict__ lsf_out,
    ushort* __restrict__ qbo, ushort* __restrict__ kbo){
  const int t0 = blockIdx.x*4;
  const int tid = threadIdx.x;
  const int lane = tid & 63, wv = tid >> 6;
  float acc[64];
  #pragma unroll
  for (int a=0;a<64;++a) acc[a]=0.f;
  const float sc = 0.08838834764831845f;  // 1/sqrt(128)
  #pragma unroll
  for (int step=0; step<3; ++step){
    const float* src = (step==0)? q : ((step==1)? k : v);
    float4 in4[4];
    #pragma unroll
    for (int r=0;r<4;++r) in4[r] = ((const float4*)src)[(size_t)(t0+r)*256 + tid];
    if (step==0){
      #pragma unroll
      for (int r=0;r<4;++r){
        ushort4 o; o.x=f2bf(in4[r].x*sc); o.y=f2bf(in4[r].y*sc);
        o.z=f2bf(in4[r].z*sc); o.w=f2bf(in4[r].w*sc);
        ((ushort4*)qbo)[(size_t)(t0+r)*256 + tid] = o;
      }
    } else if (step==1){
      #pragma unroll
      for (int r=0;r<4;++r){
        ushort4 o; o.x=f2bf(in4[r].x); o.y=f2bf(in4[r].y);
        o.z=f2bf(in4[r].z); o.w=f2bf(in4[r].w);
        ((ushort4*)kbo)[(size_t)(t0+r)*256 + tid] = o;
      }
    }
    const int wj = step*256 + tid;   // float4 index, row stride E3/4=768
    #pragma unroll
    for (int o=0;o<8;++o){
      float4 wI = ((const float4*)igw)[o*768 + wj];
      float4 wF = ((const float4*)fgw)[o*768 + wj];
      #pragma unroll
      for (int r=0;r<4;++r){
        acc[o*4+r]    = fmaf(in4[r].x, wI.x, acc[o*4+r]);
        acc[o*4+r]    = fmaf(in4[r].y, wI.y, acc[o*4+r]);
        acc[o*4+r]    = fmaf(in4[r].z, wI.z, acc[o*4+r]);
        acc[o*4+r]    = fmaf(in4[r].w, wI.w, acc[o*4+r]);
        acc[32+o*4+r] = fmaf(in4[r].x, wF.x, acc[32+o*4+r]);
        acc[32+o*4+r] = fmaf(in4[r].y, wF.y, acc[32+o*4+r]);
        acc[32+o*4+r] = fmaf(in4[r].z, wF.z, acc[32+o*4+r]);
        acc[32+o*4+r] = fmaf(in4[r].w, wF.w, acc[32+o*4+r]);
      }
    }
  }
  int cnt = 32;
  #pragma unroll
  for (int s=0; s<6; ++s){
    const bool hi = (lane >> s) & 1;
    #pragma unroll
    for (int a=0; a<32; ++a){
      if (a < cnt){
        float sent = hi ? acc[a] : acc[a+cnt];
        float got = __shfl_xor(sent, 1<<s, 64);
        acc[a] = (hi ? acc[a+cnt] : acc[a]) + got;
      }
    }
    cnt >>= 1;
  }
  __shared__ float red[4][64];
  red[wv][lane] = acc[0];
  __syncthreads();
  if (tid < 64){
    float tot = red[0][tid]+red[1][tid]+red[2][tid]+red[3][tid];
    int a = (int)(__brev((unsigned)tid) >> 26);   // bitrev6
    int f = a >> 5, o = (a>>2)&7, r = a&3;
    int t = t0 + r;
    if (f==0) ig_out[o*S_LEN + t] = tot + igb[o];
    else      lsf_out[o*S_LEN + t] = logsigf(tot + fgb[o]);
  }
}

// ---------------- Kernel B: per-head scans ---------------------------------
__global__ __launch_bounds__(256) void scan_kernel(
    const float* __restrict__ ig, const float* __restrict__ lsf,
    float* __restrict__ cs_out, float* __restrict__ M_out, float* __restrict__ m_out){
  const int h = blockIdx.x;
  const int tid = threadIdx.x;
  __shared__ float tt[256];
  const int base = tid*8;
  const float* src = lsf + h*S_LEN;
  float loc[8]; float tot = 0.f;
  #pragma unroll
  for (int i=0;i<8;++i){ tot += src[base+i]; loc[i]=tot; }
  tt[tid]=tot; __syncthreads();
  for (int off=1; off<256; off<<=1){
    float add = (tid>=off)? tt[tid-off] : 0.f;
    __syncthreads();
    tt[tid] += add;
    __syncthreads();
  }
  const float excl = tt[tid] - tot;
  float csv[8];
  #pragma unroll
  for (int i=0;i<8;++i){ csv[i] = excl + loc[i]; cs_out[h*S_LEN+base+i]=csv[i]; }
  const float* igp = ig + h*S_LEN;
  float mloc[8], mval[8]; float mtot = -INFINITY;
  #pragma unroll
  for (int i=0;i<8;++i){
    float m = igp[base+i] - csv[i];
    mval[i] = m;
    mtot = fmaxf(mtot, m);
    mloc[i] = mtot;
  }
  __syncthreads();
  tt[tid]=mtot; __syncthreads();
  for (int off=1; off<256; off<<=1){
    float add = (tid>=off)? tt[tid-off] : -INFINITY;
    __syncthreads();
    tt[tid] = fmaxf(tt[tid], add);
    __syncthreads();
  }
  const float exclm = (tid>0)? tt[tid-1] : -INFINITY;
  #pragma unroll
  for (int i=0;i<8;++i){
    M_out[h*S_LEN+base+i] = fmaxf(exclm, mloc[i]);
    m_out[h*S_LEN+base+i] = mval[i];
  }
}

// ---------------- Kernel P2: V transpose -> vt[h][d][s] bf16 ---------------
__global__ __launch_bounds__(256) void vtrans(
    const float* __restrict__ v, ushort* __restrict__ vt){
  const int s0 = blockIdx.x*64, d0 = blockIdx.y*64, h = blockIdx.z;
  __shared__ float T[64][65];
  const int r = threadIdx.x>>2, cq = threadIdx.x&3;
  #pragma unroll
  for (int i=0;i<4;++i){
    int col = cq*16 + i*4;
    float4 val = *(const float4*)(v + (size_t)(s0+r)*E_DIM + h*DH + d0 + col);
    T[r][col]=val.x; T[r][col+1]=val.y; T[r][col+2]=val.z; T[r][col+3]=val.w;
  }
  __syncthreads();
  ushort tmp[16];
  #pragma unroll
  for (int i=0;i<16;++i) tmp[i] = f2bf(T[cq*16+i][r]);
  ushort* dst = vt + ((size_t)(h*DH + d0 + r))*S_LEN + s0 + cq*16;
  uint4 o0, o1;
  ushort* p0 = (ushort*)&o0; ushort* p1 = (ushort*)&o1;
  #pragma unroll
  for (int i=0;i<8;++i){ p0[i]=tmp[i]; p1[i]=tmp[8+i]; }
  *(uint4*)dst = o0;
  *(uint4*)(dst+8) = o1;
}

// ---------------- Kernel C: fat-interval swapped-QK MFMA main --------------
// Grid (8 heads, 64 pairs). Block 512 = 8 waves, wave w owns s-slice w*16
// of each 128-s unit (no QK duplication) and FULL d=128 PV (8 accum frags).
// K staged in LDS (32KB dbuf via global_load_lds, XOR swizzle); V^T
// prefetched to regs one interval ahead; P in regs (swapped QK^T).
// Epilogue: 2-round cross-wave reduce in LDS unioned with K buffers.
__device__ __forceinline__ void stage_unit(const ushort* kbh, int u, ushort* buf, int tid){
  #pragma unroll
  for (int is=0; is<4; ++is){
    const int L = tid + is*512;
    const int r = L>>4, c = L&15;
    stage16(kbh + (size_t)(u*128 + r)*E_DIM + ((c ^ (r&7))<<3), buf + L*8);
  }
}

#define VLOAD(i) { const ushort* vp_ = vth + (size_t)((i)*16+m16)*S_LEN;     \
    vlo##i = *(const bf16x4*)(vp_ + sA);                                     \
    vhi##i = *(const bf16x4*)(vp_ + sB); }

#define VB(i) __builtin_shufflevector(vlo##i, vhi##i, 0,1,2,3,4,5,6,7)

#define PVALL(w2,w3) { bf16x8 pa_; unsigned* pau_=(unsigned*)&pa_;           \
    pau_[0]=cvtpk(pwA0,pwA1); pau_[1]=cvtpk(pwA2,pwA3);                      \
    pau_[2]=(w2); pau_[3]=(w3);                                              \
    o0=MFMA32(pa_, VB(0), o0); o1=MFMA32(pa_, VB(1), o1);                    \
    o2=MFMA32(pa_, VB(2), o2); o3=MFMA32(pa_, VB(3), o3);                    \
    o4=MFMA32(pa_, VB(4), o4); o5=MFMA32(pa_, VB(5), o5);                    \
    o6=MFMA32(pa_, VB(6), o6); o7=MFMA32(pa_, VB(7), o7); }

__global__ __launch_bounds__(512, 4) void mlstm_mfma4(
    const ushort* __restrict__ qb, const ushort* __restrict__ kb,
    const ushort* __restrict__ vt,
    const float* __restrict__ csb, const float* __restrict__ Mxb,
    const float* __restrict__ mbb,
    const float* __restrict__ nw, float* __restrict__ out){
  const int h = blockIdx.x, ip = blockIdx.y;
  const int tid = threadIdx.x, l = tid & 63, w = tid >> 6;
  const int g = l >> 4, m16 = l & 15;

  __shared__ __align__(16) float UNI[16384];    // 64 KB: K dbuf / Osum union
  __shared__ float rsL[8][16];
  ushort* Kb0 = (ushort*)UNI;
  ushort* Kb1 = Kb0 + 16384;                    // +32 KB
  float*  Osum = UNI;                           // [8 waves][16 q][68]

  const ushort* kbh = kb + h*DH;
  const ushort* vth = vt + (size_t)h*DH*S_LEN;
  const float*  mh  = mbb + h*S_LEN;
  const int hS = h*S_LEN;

  for (int pass=0; pass<2; ++pass){
    const int qt16 = pass ? (127 - ip) : ip;
    const int t0 = qt16*16;
    const int NU = (qt16>>3) + 1;               // 128-s units
    const int tg = t0 + m16;
    const float Mq = Mxb[hS + tg];

    bf16x8 qf0,qf1,qf2,qf3;
    { const ushort* qs = qb + (size_t)tg*E_DIM + h*DH + g*8;
      qf0 = *(const bf16x8*)qs;
      qf1 = *(const bf16x8*)(qs+32);
      qf2 = *(const bf16x8*)(qs+64);
      qf3 = *(const bf16x8*)(qs+96); }

    f32x4 o0={0.f,0.f,0.f,0.f}, o1=o0, o2=o0, o3=o0, o4=o0, o5=o0, o6=o0, o7=o0;
    float rsq = 0.f;
    float pwA0=0.f, pwA1=0.f, pwA2=0.f, pwA3=0.f;
    bf16x4 vlo0,vlo1,vlo2,vlo3,vlo4,vlo5,vlo6,vlo7;
    bf16x4 vhi0,vhi1,vhi2,vhi3,vhi4,vhi5,vhi6,vhi7;

    stage_unit(kbh, 0, Kb0, tid);               // prologue (post-epilogue barrier)

    for (int u=0; u<NU; ++u){
      __syncthreads();                          // stage(u) landed
      if (u+1 < NU){
        stage_unit(kbh, u+1, ((u+1)&1) ? Kb1 : Kb0, tid);
      }
      if (!(u&1)){                              // V prefetch for pair (u,u+1)
        const int sA = u*128 + w*16 + g*4;
        const int sB = sA + 128;                // in-bounds: (u+1)<=15 -> <2048
        VLOAD(0) VLOAD(1) VLOAD(2) VLOAD(3)
        VLOAD(4) VLOAD(5) VLOAD(6) VLOAD(7)
      }
      // ---- QK^T on this wave's 16-s slice of unit u ----
      const ushort* kbuf = (u&1) ? Kb1 : Kb0;
      const int row = w*16 + m16;
      const int rx = m16 & 7;                   // row&7 == m16&7
      const ushort* kbase = kbuf + row*128;
      bf16x8 ka0 = *(const bf16x8*)(kbase + (((0*4+g) ^ rx)<<3));
      bf16x8 ka1 = *(const bf16x8*)(kbase + (((1*4+g) ^ rx)<<3));
      bf16x8 ka2 = *(const bf16x8*)(kbase + (((2*4+g) ^ rx)<<3));
      bf16x8 ka3 = *(const bf16x8*)(kbase + (((3*4+g) ^ rx)<<3));
      f32x4 c0={0.f,0.f,0.f,0.f}, c1=c0;
      c0 = MFMA32(ka0, qf0, c0);
      c1 = MFMA32(ka1, qf1, c1);
      c0 = MFMA32(ka2, qf2, c0);
      c1 = MFMA32(ka3, qf3, c1);
      const int sgb = u*128 + w*16 + g*4;
      const f32x4 m4 = *(const f32x4*)(mh + sgb);
      float pw0 = (sgb+0 <= tg) ? (c0[0]+c1[0])*__expf(m4[0]-Mq) : 0.f;
      float pw1 = (sgb+1 <= tg) ? (c0[1]+c1[1])*__expf(m4[1]-Mq) : 0.f;
      float pw2 = (sgb+2 <= tg) ? (c0[2]+c1[2])*__expf(m4[2]-Mq) : 0.f;
      float pw3 = (sgb+3 <= tg) ? (c0[3]+c1[3])*__expf(m4[3]-Mq) : 0.f;
      rsq += pw0+pw1+pw2+pw3;
      if (u & 1){
        PVALL(cvtpk(pw0,pw1), cvtpk(pw2,pw3));
      } else {
        pwA0=pw0; pwA1=pw1; pwA2=pw2; pwA3=pw3;
      }
    }
    if (NU & 1){                                // odd tail: upper K-half zero
      PVALL(0u, 0u);
    }

    // -------- epilogue: 2-round cross-wave reduce + normalizer + LN --------
    __syncthreads();                            // K LDS reads done; union free
    rsq += __shfl_xor(rsq, 16, 64);
    rsq += __shfl_xor(rsq, 32, 64);
    if (l < 16) rsL[w][m16] = rsq;

    float* ob = Osum + w*1088;                  // 16*68
    #pragma unroll
    for (int r=0;r<4;++r){
      const int qrow = g*4+r;
      ob[qrow*68 + 0*16 + m16] = o0[r];
      ob[qrow*68 + 1*16 + m16] = o1[r];
      ob[qrow*68 + 2*16 + m16] = o2[r];
      ob[qrow*68 + 3*16 + m16] = o3[r];
    }
    __syncthreads();

    const bool act = (tid < 256);
    const int qr = tid >> 4, dc = tid & 15;
    float iv = 0.f, s1 = 0.f, s2 = 0.f;
    f32x4 hvA={0.f,0.f,0.f,0.f}, hvB={0.f,0.f,0.f,0.f};
    if (act){
      f32x4 os = {0.f,0.f,0.f,0.f};
      #pragma unroll
      for (int wv=0; wv<8; ++wv){
        const f32x4 part = *(const f32x4*)&Osum[wv*1088 + qr*68 + dc*4];
        os[0]+=part[0]; os[1]+=part[1]; os[2]+=part[2]; os[3]+=part[3];
      }
      float rstot = 0.f;
      #pragma unroll
      for (int wv=0; wv<8; ++wv) rstot += rsL[wv][qr];
      const int tq = t0 + qr;
      const float en = __expf(-(csb[hS+tq] + Mxb[hS+tq]));
      iv = 1.f/(fmaxf(fabsf(rstot), en) + 1e-6f);
      hvA[0]=os[0]*iv; hvA[1]=os[1]*iv; hvA[2]=os[2]*iv; hvA[3]=os[3]*iv;
      s1 += hvA[0]+hvA[1]+hvA[2]+hvA[3];
      s2 += hvA[0]*hvA[0]+hvA[1]*hvA[1]+hvA[2]*hvA[2]+hvA[3]*hvA[3];
    }
    __syncthreads();                            // Osum round-0 reads done
    #pragma unroll
    for (int r=0;r<4;++r){
      const int qrow = g*4+r;
      ob[qrow*68 + 0*16 + m16] = o4[r];
      ob[qrow*68 + 1*16 + m16] = o5[r];
      ob[qrow*68 + 2*16 + m16] = o6[r];
      ob[qrow*68 + 3*16 + m16] = o7[r];
    }
    __syncthreads();
    if (act){
      f32x4 os = {0.f,0.f,0.f,0.f};
      #pragma unroll
      for (int wv=0; wv<8; ++wv){
        const f32x4 part = *(const f32x4*)&Osum[wv*1088 + qr*68 + dc*4];
        os[0]+=part[0]; os[1]+=part[1]; os[2]+=part[2]; os[3]+=part[3];
      }
      hvB[0]=os[0]*iv; hvB[1]=os[1]*iv; hvB[2]=os[2]*iv; hvB[3]=os[3]*iv;
      s1 += hvB[0]+hvB[1]+hvB[2]+hvB[3];
      s2 += hvB[0]*hvB[0]+hvB[1]*hvB[1]+hvB[2]*hvB[2]+hvB[3]*hvB[3];
      s1 += __shfl_xor(s1, 1, 64);  s2 += __shfl_xor(s2, 1, 64);
      s1 += __shfl_xor(s1, 2, 64);  s2 += __shfl_xor(s2, 2, 64);
      s1 += __shfl_xor(s1, 4, 64);  s2 += __shfl_xor(s2, 4, 64);
      s1 += __shfl_xor(s1, 8, 64);  s2 += __shfl_xor(s2, 8, 64);
      const float mean = s1 * (1.f/128.f);
      const float var  = s2 * (1.f/128.f) - mean*mean;
      const float rstd = rsqrtf(var + 1e-5f);
      const int tq = t0 + qr;
      float* orow = out + (size_t)tq*E_DIM + h*DH;
      const f32x4 nwA = *(const f32x4*)(nw + h*DH + dc*4);
      const f32x4 nwB = *(const f32x4*)(nw + h*DH + 64 + dc*4);
      f32x4 oA, oB;
      oA[0]=(hvA[0]-mean)*rstd*nwA[0]; oA[1]=(hvA[1]-mean)*rstd*nwA[1];
      oA[2]=(hvA[2]-mean)*rstd*nwA[2]; oA[3]=(hvA[3]-mean)*rstd*nwA[3];
      oB[0]=(hvB[0]-mean)*rstd*nwB[0]; oB[1]=(hvB[1]-mean)*rstd*nwB[1];
      oB[2]=(hvB[2]-mean)*rstd*nwB[2]; oB[3]=(hvB[3]-mean)*rstd*nwB[3];
      *(f32x4*)(orow + dc*4) = oA;
      *(f32x4*)(orow + 64 + dc*4) = oB;
    }
    __syncthreads();                            // Osum free before next pass
  }
}

extern "C" void kernel_launch(void* const* d_in, const int* in_sizes, int n_in,
                              void* d_out, int out_size, void* d_ws, size_t ws_size,
                              hipStream_t stream) {
  const float* q   = (const float*)d_in[0];
  const float* k   = (const float*)d_in[1];
  const float* v   = (const float*)d_in[2];
  const float* igw = (const float*)d_in[3];
  const float* igb = (const float*)d_in[4];
  const float* fgw = (const float*)d_in[5];
  const float* fgb = (const float*)d_in[6];
  const float* nw  = (const float*)d_in[7];
  float* outp = (float*)d_out;

  float* ws  = (float*)d_ws;
  float* ig  = ws;                 // NH*S
  float* lsf = ws + 1*NHEAD*S_LEN;
  float* csb = ws + 2*NHEAD*S_LEN;
  float* Mb  = ws + 3*NHEAD*S_LEN;
  float* mbf = ws + 4*NHEAD*S_LEN;
  ushort* qbb = (ushort*)(ws + 5*NHEAD*S_LEN);          // S*E bf16 (scaled)
  ushort* kbb = qbb + (size_t)S_LEN*E_DIM;              // S*E bf16
  ushort* vtb = kbb + (size_t)S_LEN*E_DIM;              // E*S bf16 (per-head V^T)

  gates_qk<<<512, 256, 0, stream>>>(q, k, v, igw, igb, fgw, fgb, ig, lsf, qbb, kbb);
  scan_kernel<<<NHEAD, 256, 0, stream>>>(ig, lsf, csb, Mb, mbf);
  vtrans<<<dim3(S_LEN/64, DH/64, NHEAD), 256, 0, stream>>>(v, vtb);
  mlstm_mfma4<<<dim3(NHEAD, 64), 512, 0, stream>>>(qbb, kbb, vtb, csb, Mb, mbf, nw, outp);
}

// Round 7
// 129.145 us; speedup vs baseline: 1.0880x; 1.0880x over previous
//
#include <hip/hip_runtime.h>
#include <hip/hip_bf16.h>
#include <math.h>

#define S_LEN 2048
#define E_DIM 1024
#define NHEAD 8
#define DH 128
#define E3 3072

typedef short bf16x8 __attribute__((ext_vector_type(8)));
typedef short bf16x4 __attribute__((ext_vector_type(4)));
typedef float f32x4 __attribute__((ext_vector_type(4)));

#define MFMA32(a,b,c) __builtin_amdgcn_mfma_f32_16x16x32_bf16(a,b,c,0,0,0)

__device__ __forceinline__ unsigned short f2bf(float f){
  union{float f; unsigned u;} x; x.f = f;
  unsigned r = x.u + 0x7FFF + ((x.u>>16)&1);
  return (unsigned short)(r>>16);
}

__device__ __forceinline__ unsigned cvtpk(float lo, float hi){
  unsigned r;
  asm("v_cvt_pk_bf16_f32 %0, %1, %2" : "=v"(r) : "v"(lo), "v"(hi));
  return r;
}

__device__ __forceinline__ float logsigf(float x){
  return fminf(x, 0.f) - log1pf(expf(-fabsf(x)));
}

typedef const __attribute__((address_space(1))) unsigned int* gas1_t;
typedef __attribute__((address_space(3))) unsigned int* las3_t;
__device__ __forceinline__ void stage16(const ushort* g, ushort* l){
  __builtin_amdgcn_global_load_lds((gas1_t)(const void*)g, (las3_t)(void*)l, 16, 0, 0);
}

// ---------------- Kernel A: gates + q/k bf16 conversion (fused) ------------
__global__ __launch_bounds__(256) void gates_qk(
    const float* __restrict__ q, const float* __restrict__ k, const float* __restrict__ v,
    const float* __restrict__ igw, const float* __restrict__ igb,
    const float* __restrict__ fgw, const float* __restrict__ fgb,
    float* __restrict__ ig_out, float* __restrict__ lsf_out,
    ushort* __restrict__ qbo, ushort* __restrict__ kbo){
  const int t0 = blockIdx.x*4;
  const int tid = threadIdx.x;
  const int lane = tid & 63, wv = tid >> 6;
  float acc[64];
  #pragma unroll
  for (int a=0;a<64;++a) acc[a]=0.f;
  const float sc = 0.08838834764831845f;  // 1/sqrt(128)
  #pragma unroll
  for (int step=0; step<3; ++step){
    const float* src = (step==0)? q : ((step==1)? k : v);
    float4 in4[4];
    #pragma unroll
    for (int r=0;r<4;++r) in4[r] = ((const float4*)src)[(size_t)(t0+r)*256 + tid];
    if (step==0){
      #pragma unroll
      for (int r=0;r<4;++r){
        ushort4 o; o.x=f2bf(in4[r].x*sc); o.y=f2bf(in4[r].y*sc);
        o.z=f2bf(in4[r].z*sc); o.w=f2bf(in4[r].w*sc);
        ((ushort4*)qbo)[(size_t)(t0+r)*256 + tid] = o;
      }
    } else if (step==1){
      #pragma unroll
      for (int r=0;r<4;++r){
        ushort4 o; o.x=f2bf(in4[r].x); o.y=f2bf(in4[r].y);
        o.z=f2bf(in4[r].z); o.w=f2bf(in4[r].w);
        ((ushort4*)kbo)[(size_t)(t0+r)*256 + tid] = o;
      }
    }
    const int wj = step*256 + tid;   // float4 index, row stride E3/4=768
    #pragma unroll
    for (int o=0;o<8;++o){
      float4 wI = ((const float4*)igw)[o*768 + wj];
      float4 wF = ((const float4*)fgw)[o*768 + wj];
      #pragma unroll
      for (int r=0;r<4;++r){
        acc[o*4+r]    = fmaf(in4[r].x, wI.x, acc[o*4+r]);
        acc[o*4+r]    = fmaf(in4[r].y, wI.y, acc[o*4+r]);
        acc[o*4+r]    = fmaf(in4[r].z, wI.z, acc[o*4+r]);
        acc[o*4+r]    = fmaf(in4[r].w, wI.w, acc[o*4+r]);
        acc[32+o*4+r] = fmaf(in4[r].x, wF.x, acc[32+o*4+r]);
        acc[32+o*4+r] = fmaf(in4[r].y, wF.y, acc[32+o*4+r]);
        acc[32+o*4+r] = fmaf(in4[r].z, wF.z, acc[32+o*4+r]);
        acc[32+o*4+r] = fmaf(in4[r].w, wF.w, acc[32+o*4+r]);
      }
    }
  }
  int cnt = 32;
  #pragma unroll
  for (int s=0; s<6; ++s){
    const bool hi = (lane >> s) & 1;
    #pragma unroll
    for (int a=0; a<32; ++a){
      if (a < cnt){
        float sent = hi ? acc[a] : acc[a+cnt];
        float got = __shfl_xor(sent, 1<<s, 64);
        acc[a] = (hi ? acc[a+cnt] : acc[a]) + got;
      }
    }
    cnt >>= 1;
  }
  __shared__ float red[4][64];
  red[wv][lane] = acc[0];
  __syncthreads();
  if (tid < 64){
    float tot = red[0][tid]+red[1][tid]+red[2][tid]+red[3][tid];
    int a = (int)(__brev((unsigned)tid) >> 26);   // bitrev6
    int f = a >> 5, o = (a>>2)&7, r = a&3;
    int t = t0 + r;
    if (f==0) ig_out[o*S_LEN + t] = tot + igb[o];
    else      lsf_out[o*S_LEN + t] = logsigf(tot + fgb[o]);
  }
}

// ---------------- Kernel B: per-head scans ---------------------------------
__global__ __launch_bounds__(256) void scan_kernel(
    const float* __restrict__ ig, const float* __restrict__ lsf,
    float* __restrict__ cs_out, float* __restrict__ M_out, float* __restrict__ m_out){
  const int h = blockIdx.x;
  const int tid = threadIdx.x;
  __shared__ float tt[256];
  const int base = tid*8;
  const float* src = lsf + h*S_LEN;
  float loc[8]; float tot = 0.f;
  #pragma unroll
  for (int i=0;i<8;++i){ tot += src[base+i]; loc[i]=tot; }
  tt[tid]=tot; __syncthreads();
  for (int off=1; off<256; off<<=1){
    float add = (tid>=off)? tt[tid-off] : 0.f;
    __syncthreads();
    tt[tid] += add;
    __syncthreads();
  }
  const float excl = tt[tid] - tot;
  float csv[8];
  #pragma unroll
  for (int i=0;i<8;++i){ csv[i] = excl + loc[i]; cs_out[h*S_LEN+base+i]=csv[i]; }
  const float* igp = ig + h*S_LEN;
  float mloc[8], mval[8]; float mtot = -INFINITY;
  #pragma unroll
  for (int i=0;i<8;++i){
    float m = igp[base+i] - csv[i];
    mval[i] = m;
    mtot = fmaxf(mtot, m);
    mloc[i] = mtot;
  }
  __syncthreads();
  tt[tid]=mtot; __syncthreads();
  for (int off=1; off<256; off<<=1){
    float add = (tid>=off)? tt[tid-off] : -INFINITY;
    __syncthreads();
    tt[tid] = fmaxf(tt[tid], add);
    __syncthreads();
  }
  const float exclm = (tid>0)? tt[tid-1] : -INFINITY;
  #pragma unroll
  for (int i=0;i<8;++i){
    M_out[h*S_LEN+base+i] = fmaxf(exclm, mloc[i]);
    m_out[h*S_LEN+base+i] = mval[i];
  }
}

// ---------------- Kernel P2: V transpose -> vt[h][d][s] bf16 ---------------
__global__ __launch_bounds__(256) void vtrans(
    const float* __restrict__ v, ushort* __restrict__ vt){
  const int s0 = blockIdx.x*64, d0 = blockIdx.y*64, h = blockIdx.z;
  __shared__ float T[64][65];
  const int r = threadIdx.x>>2, cq = threadIdx.x&3;
  #pragma unroll
  for (int i=0;i<4;++i){
    int col = cq*16 + i*4;
    float4 val = *(const float4*)(v + (size_t)(s0+r)*E_DIM + h*DH + d0 + col);
    T[r][col]=val.x; T[r][col+1]=val.y; T[r][col+2]=val.z; T[r][col+3]=val.w;
  }
  __syncthreads();
  ushort tmp[16];
  #pragma unroll
  for (int i=0;i<16;++i) tmp[i] = f2bf(T[cq*16+i][r]);
  ushort* dst = vt + ((size_t)(h*DH + d0 + r))*S_LEN + s0 + cq*16;
  uint4 o0, o1;
  ushort* p0 = (ushort*)&o0; ushort* p1 = (ushort*)&o1;
  #pragma unroll
  for (int i=0;i<8;++i){ p0[i]=tmp[i]; p1[i]=tmp[8+i]; }
  *(uint4*)dst = o0;
  *(uint4*)(dst+8) = o1;
}

// ---------------- Kernel C: fat-interval swapped-QK MFMA main --------------
// Identical to round-6 structure; ONLY the launch bounds changed:
// (512,4) empirically caps VGPR at 64 on this compiler -> 43MB of spill
// traffic. (512,2) gives the ~110-reg demand a 128-reg budget; occupancy
// is LDS-limited to 2 blocks/CU either way.
__device__ __forceinline__ void stage_unit(const ushort* kbh, int u, ushort* buf, int tid){
  #pragma unroll
  for (int is=0; is<4; ++is){
    const int L = tid + is*512;
    const int r = L>>4, c = L&15;
    stage16(kbh + (size_t)(u*128 + r)*E_DIM + ((c ^ (r&7))<<3), buf + L*8);
  }
}

#define VLOAD(i) { const ushort* vp_ = vth + (size_t)((i)*16+m16)*S_LEN;     \
    vlo##i = *(const bf16x4*)(vp_ + sA);                                     \
    vhi##i = *(const bf16x4*)(vp_ + sB); }

#define VB(i) __builtin_shufflevector(vlo##i, vhi##i, 0,1,2,3,4,5,6,7)

#define PVALL(w2,w3) { bf16x8 pa_; unsigned* pau_=(unsigned*)&pa_;           \
    pau_[0]=cvtpk(pwA0,pwA1); pau_[1]=cvtpk(pwA2,pwA3);                      \
    pau_[2]=(w2); pau_[3]=(w3);                                              \
    o0=MFMA32(pa_, VB(0), o0); o1=MFMA32(pa_, VB(1), o1);                    \
    o2=MFMA32(pa_, VB(2), o2); o3=MFMA32(pa_, VB(3), o3);                    \
    o4=MFMA32(pa_, VB(4), o4); o5=MFMA32(pa_, VB(5), o5);                    \
    o6=MFMA32(pa_, VB(6), o6); o7=MFMA32(pa_, VB(7), o7); }

__global__ __launch_bounds__(512, 2) void mlstm_mfma4(
    const ushort* __restrict__ qb, const ushort* __restrict__ kb,
    const ushort* __restrict__ vt,
    const float* __restrict__ csb, const float* __restrict__ Mxb,
    const float* __restrict__ mbb,
    const float* __restrict__ nw, float* __restrict__ out){
  const int h = blockIdx.x, ip = blockIdx.y;
  const int tid = threadIdx.x, l = tid & 63, w = tid >> 6;
  const int g = l >> 4, m16 = l & 15;

  __shared__ __align__(16) float UNI[16384];    // 64 KB: K dbuf / Osum union
  __shared__ float rsL[8][16];
  ushort* Kb0 = (ushort*)UNI;
  ushort* Kb1 = Kb0 + 16384;                    // +32 KB
  float*  Osum = UNI;                           // [8 waves][16 q][68]

  const ushort* kbh = kb + h*DH;
  const ushort* vth = vt + (size_t)h*DH*S_LEN;
  const float*  mh  = mbb + h*S_LEN;
  const int hS = h*S_LEN;

  for (int pass=0; pass<2; ++pass){
    const int qt16 = pass ? (127 - ip) : ip;
    const int t0 = qt16*16;
    const int NU = (qt16>>3) + 1;               // 128-s units
    const int tg = t0 + m16;
    const float Mq = Mxb[hS + tg];

    bf16x8 qf0,qf1,qf2,qf3;
    { const ushort* qs = qb + (size_t)tg*E_DIM + h*DH + g*8;
      qf0 = *(const bf16x8*)qs;
      qf1 = *(const bf16x8*)(qs+32);
      qf2 = *(const bf16x8*)(qs+64);
      qf3 = *(const bf16x8*)(qs+96); }

    f32x4 o0={0.f,0.f,0.f,0.f}, o1=o0, o2=o0, o3=o0, o4=o0, o5=o0, o6=o0, o7=o0;
    float rsq = 0.f;
    float pwA0=0.f, pwA1=0.f, pwA2=0.f, pwA3=0.f;
    bf16x4 vlo0,vlo1,vlo2,vlo3,vlo4,vlo5,vlo6,vlo7;
    bf16x4 vhi0,vhi1,vhi2,vhi3,vhi4,vhi5,vhi6,vhi7;

    stage_unit(kbh, 0, Kb0, tid);               // prologue (post-epilogue barrier)

    for (int u=0; u<NU; ++u){
      __syncthreads();                          // stage(u) landed
      if (u+1 < NU){
        stage_unit(kbh, u+1, ((u+1)&1) ? Kb1 : Kb0, tid);
      }
      if (!(u&1)){                              // V prefetch for pair (u,u+1)
        const int sA = u*128 + w*16 + g*4;
        const int sB = sA + 128;                // in-bounds: (u+1)<=15 -> <2048
        VLOAD(0) VLOAD(1) VLOAD(2) VLOAD(3)
        VLOAD(4) VLOAD(5) VLOAD(6) VLOAD(7)
      }
      // ---- QK^T on this wave's 16-s slice of unit u ----
      const ushort* kbuf = (u&1) ? Kb1 : Kb0;
      const int row = w*16 + m16;
      const int rx = m16 & 7;                   // row&7 == m16&7
      const ushort* kbase = kbuf + row*128;
      bf16x8 ka0 = *(const bf16x8*)(kbase + (((0*4+g) ^ rx)<<3));
      bf16x8 ka1 = *(const bf16x8*)(kbase + (((1*4+g) ^ rx)<<3));
      bf16x8 ka2 = *(const bf16x8*)(kbase + (((2*4+g) ^ rx)<<3));
      bf16x8 ka3 = *(const bf16x8*)(kbase + (((3*4+g) ^ rx)<<3));
      f32x4 c0={0.f,0.f,0.f,0.f}, c1=c0;
      c0 = MFMA32(ka0, qf0, c0);
      c1 = MFMA32(ka1, qf1, c1);
      c0 = MFMA32(ka2, qf2, c0);
      c1 = MFMA32(ka3, qf3, c1);
      const int sgb = u*128 + w*16 + g*4;
      const f32x4 m4 = *(const f32x4*)(mh + sgb);
      float pw0 = (sgb+0 <= tg) ? (c0[0]+c1[0])*__expf(m4[0]-Mq) : 0.f;
      float pw1 = (sgb+1 <= tg) ? (c0[1]+c1[1])*__expf(m4[1]-Mq) : 0.f;
      float pw2 = (sgb+2 <= tg) ? (c0[2]+c1[2])*__expf(m4[2]-Mq) : 0.f;
      float pw3 = (sgb+3 <= tg) ? (c0[3]+c1[3])*__expf(m4[3]-Mq) : 0.f;
      rsq += pw0+pw1+pw2+pw3;
      if (u & 1){
        PVALL(cvtpk(pw0,pw1), cvtpk(pw2,pw3));
      } else {
        pwA0=pw0; pwA1=pw1; pwA2=pw2; pwA3=pw3;
      }
    }
    if (NU & 1){                                // odd tail: upper K-half zero
      PVALL(0u, 0u);
    }

    // -------- epilogue: 2-round cross-wave reduce + normalizer + LN --------
    __syncthreads();                            // K LDS reads done; union free
    rsq += __shfl_xor(rsq, 16, 64);
    rsq += __shfl_xor(rsq, 32, 64);
    if (l < 16) rsL[w][m16] = rsq;

    float* ob = Osum + w*1088;                  // 16*68
    #pragma unroll
    for (int r=0;r<4;++r){
      const int qrow = g*4+r;
      ob[qrow*68 + 0*16 + m16] = o0[r];
      ob[qrow*68 + 1*16 + m16] = o1[r];
      ob[qrow*68 + 2*16 + m16] = o2[r];
      ob[qrow*68 + 3*16 + m16] = o3[r];
    }
    __syncthreads();

    const bool act = (tid < 256);
    const int qr = tid >> 4, dc = tid & 15;
    float iv = 0.f, s1 = 0.f, s2 = 0.f;
    f32x4 hvA={0.f,0.f,0.f,0.f}, hvB={0.f,0.f,0.f,0.f};
    if (act){
      f32x4 os = {0.f,0.f,0.f,0.f};
      #pragma unroll
      for (int wv=0; wv<8; ++wv){
        const f32x4 part = *(const f32x4*)&Osum[wv*1088 + qr*68 + dc*4];
        os[0]+=part[0]; os[1]+=part[1]; os[2]+=part[2]; os[3]+=part[3];
      }
      float rstot = 0.f;
      #pragma unroll
      for (int wv=0; wv<8; ++wv) rstot += rsL[wv][qr];
      const int tq = t0 + qr;
      const float en = __expf(-(csb[hS+tq] + Mxb[hS+tq]));
      iv = 1.f/(fmaxf(fabsf(rstot), en) + 1e-6f);
      hvA[0]=os[0]*iv; hvA[1]=os[1]*iv; hvA[2]=os[2]*iv; hvA[3]=os[3]*iv;
      s1 += hvA[0]+hvA[1]+hvA[2]+hvA[3];
      s2 += hvA[0]*hvA[0]+hvA[1]*hvA[1]+hvA[2]*hvA[2]+hvA[3]*hvA[3];
    }
    __syncthreads();                            // Osum round-0 reads done
    #pragma unroll
    for (int r=0;r<4;++r){
      const int qrow = g*4+r;
      ob[qrow*68 + 0*16 + m16] = o4[r];
      ob[qrow*68 + 1*16 + m16] = o5[r];
      ob[qrow*68 + 2*16 + m16] = o6[r];
      ob[qrow*68 + 3*16 + m16] = o7[r];
    }
    __syncthreads();
    if (act){
      f32x4 os = {0.f,0.f,0.f,0.f};
      #pragma unroll
      for (int wv=0; wv<8; ++wv){
        const f32x4 part = *(const f32x4*)&Osum[wv*1088 + qr*68 + dc*4];
        os[0]+=part[0]; os[1]+=part[1]; os[2]+=part[2]; os[3]+=part[3];
      }
      hvB[0]=os[0]*iv; hvB[1]=os[1]*iv; hvB[2]=os[2]*iv; hvB[3]=os[3]*iv;
      s1 += hvB[0]+hvB[1]+hvB[2]+hvB[3];
      s2 += hvB[0]*hvB[0]+hvB[1]*hvB[1]+hvB[2]*hvB[2]+hvB[3]*hvB[3];
      s1 += __shfl_xor(s1, 1, 64);  s2 += __shfl_xor(s2, 1, 64);
      s1 += __shfl_xor(s1, 2, 64);  s2 += __shfl_xor(s2, 2, 64);
      s1 += __shfl_xor(s1, 4, 64);  s2 += __shfl_xor(s2, 4, 64);
      s1 += __shfl_xor(s1, 8, 64);  s2 += __shfl_xor(s2, 8, 64);
      const float mean = s1 * (1.f/128.f);
      const float var  = s2 * (1.f/128.f) - mean*mean;
      const float rstd = rsqrtf(var + 1e-5f);
      const int tq = t0 + qr;
      float* orow = out + (size_t)tq*E_DIM + h*DH;
      const f32x4 nwA = *(const f32x4*)(nw + h*DH + dc*4);
      const f32x4 nwB = *(const f32x4*)(nw + h*DH + 64 + dc*4);
      f32x4 oA, oB;
      oA[0]=(hvA[0]-mean)*rstd*nwA[0]; oA[1]=(hvA[1]-mean)*rstd*nwA[1];
      oA[2]=(hvA[2]-mean)*rstd*nwA[2]; oA[3]=(hvA[3]-mean)*rstd*nwA[3];
      oB[0]=(hvB[0]-mean)*rstd*nwB[0]; oB[1]=(hvB[1]-mean)*rstd*nwB[1];
      oB[2]=(hvB[2]-mean)*rstd*nwB[2]; oB[3]=(hvB[3]-mean)*rstd*nwB[3];
      *(f32x4*)(orow + dc*4) = oA;
      *(f32x4*)(orow + 64 + dc*4) = oB;
    }
    __syncthreads();                            // Osum free before next pass
  }
}

extern "C" void kernel_launch(void* const* d_in, const int* in_sizes, int n_in,
                              void* d_out, int out_size, void* d_ws, size_t ws_size,
                              hipStream_t stream) {
  const float* q   = (const float*)d_in[0];
  const float* k   = (const float*)d_in[1];
  const float* v   = (const float*)d_in[2];
  const float* igw = (const float*)d_in[3];
  const float* igb = (const float*)d_in[4];
  const float* fgw = (const float*)d_in[5];
  const float* fgb = (const float*)d_in[6];
  const float* nw  = (const float*)d_in[7];
  float* outp = (float*)d_out;

  float* ws  = (float*)d_ws;
  float* ig  = ws;                 // NH*S
  float* lsf = ws + 1*NHEAD*S_LEN;
  float* csb = ws + 2*NHEAD*S_LEN;
  float* Mb  = ws + 3*NHEAD*S_LEN;
  float* mbf = ws + 4*NHEAD*S_LEN;
  ushort* qbb = (ushort*)(ws + 5*NHEAD*S_LEN);          // S*E bf16 (scaled)
  ushort* kbb = qbb + (size_t)S_LEN*E_DIM;              // S*E bf16
  ushort* vtb = kbb + (size_t)S_LEN*E_DIM;              // E*S bf16 (per-head V^T)

  gates_qk<<<512, 256, 0, stream>>>(q, k, v, igw, igb, fgw, fgb, ig, lsf, qbb, kbb);
  scan_kernel<<<NHEAD, 256, 0, stream>>>(ig, lsf, csb, Mb, mbf);
  vtrans<<<dim3(S_LEN/64, DH/64, NHEAD), 256, 0, stream>>>(v, vtb);
  mlstm_mfma4<<<dim3(NHEAD, 64), 512, 0, stream>>>(qbb, kbb, vtb, csb, Mb, mbf, nw, outp);
}

// Round 8
// 102.757 us; speedup vs baseline: 1.3674x; 1.2568x over previous
//
#include <hip/hip_runtime.h>
#include <hip/hip_bf16.h>
#include <math.h>

#define S_LEN 2048
#define E_DIM 1024
#define NHEAD 8
#define DH 128
#define E3 3072

typedef short bf16x8 __attribute__((ext_vector_type(8)));
typedef short bf16x4 __attribute__((ext_vector_type(4)));
typedef float f32x4 __attribute__((ext_vector_type(4)));
typedef float f32x16 __attribute__((ext_vector_type(16)));

#define MFMA3216(a,b,c) __builtin_amdgcn_mfma_f32_32x32x16_bf16(a,b,c,0,0,0)
#define Z16 {0.f,0.f,0.f,0.f,0.f,0.f,0.f,0.f,0.f,0.f,0.f,0.f,0.f,0.f,0.f,0.f}
#define CROW(r) (((r)&3) + 8*((r)>>2))

__device__ __forceinline__ unsigned short f2bf(float f){
  union{float f; unsigned u;} x; x.f = f;
  unsigned r = x.u + 0x7FFF + ((x.u>>16)&1);
  return (unsigned short)(r>>16);
}

__device__ __forceinline__ unsigned cvtpk(float lo, float hi){
  unsigned r;
  asm("v_cvt_pk_bf16_f32 %0, %1, %2" : "=v"(r) : "v"(lo), "v"(hi));
  return r;
}

__device__ __forceinline__ float logsigf(float x){
  return fminf(x, 0.f) - log1pf(expf(-fabsf(x)));
}

typedef const __attribute__((address_space(1))) unsigned int* gas1_t;
typedef __attribute__((address_space(3))) unsigned int* las3_t;
__device__ __forceinline__ void stage16(const ushort* g, ushort* l){
  __builtin_amdgcn_global_load_lds((gas1_t)(const void*)g, (las3_t)(void*)l, 16, 0, 0);
}

// ---------------- Kernel A: gates + q/k bf16 conversion (fused) ------------
__global__ __launch_bounds__(256) void gates_qk(
    const float* __restrict__ q, const float* __restrict__ k, const float* __restrict__ v,
    const float* __restrict__ igw, const float* __restrict__ igb,
    const float* __restrict__ fgw, const float* __restrict__ fgb,
    float* __restrict__ ig_out, float* __restrict__ lsf_out,
    ushort* __restrict__ qbo, ushort* __restrict__ kbo){
  const int t0 = blockIdx.x*4;
  const int tid = threadIdx.x;
  const int lane = tid & 63, wv = tid >> 6;
  float acc[64];
  #pragma unroll
  for (int a=0;a<64;++a) acc[a]=0.f;
  const float sc = 0.08838834764831845f;  // 1/sqrt(128)
  #pragma unroll
  for (int step=0; step<3; ++step){
    const float* src = (step==0)? q : ((step==1)? k : v);
    float4 in4[4];
    #pragma unroll
    for (int r=0;r<4;++r) in4[r] = ((const float4*)src)[(size_t)(t0+r)*256 + tid];
    if (step==0){
      #pragma unroll
      for (int r=0;r<4;++r){
        ushort4 o; o.x=f2bf(in4[r].x*sc); o.y=f2bf(in4[r].y*sc);
        o.z=f2bf(in4[r].z*sc); o.w=f2bf(in4[r].w*sc);
        ((ushort4*)qbo)[(size_t)(t0+r)*256 + tid] = o;
      }
    } else if (step==1){
      #pragma unroll
      for (int r=0;r<4;++r){
        ushort4 o; o.x=f2bf(in4[r].x); o.y=f2bf(in4[r].y);
        o.z=f2bf(in4[r].z); o.w=f2bf(in4[r].w);
        ((ushort4*)kbo)[(size_t)(t0+r)*256 + tid] = o;
      }
    }
    const int wj = step*256 + tid;
    #pragma unroll
    for (int o=0;o<8;++o){
      float4 wI = ((const float4*)igw)[o*768 + wj];
      float4 wF = ((const float4*)fgw)[o*768 + wj];
      #pragma unroll
      for (int r=0;r<4;++r){
        acc[o*4+r]    = fmaf(in4[r].x, wI.x, acc[o*4+r]);
        acc[o*4+r]    = fmaf(in4[r].y, wI.y, acc[o*4+r]);
        acc[o*4+r]    = fmaf(in4[r].z, wI.z, acc[o*4+r]);
        acc[o*4+r]    = fmaf(in4[r].w, wI.w, acc[o*4+r]);
        acc[32+o*4+r] = fmaf(in4[r].x, wF.x, acc[32+o*4+r]);
        acc[32+o*4+r] = fmaf(in4[r].y, wF.y, acc[32+o*4+r]);
        acc[32+o*4+r] = fmaf(in4[r].z, wF.z, acc[32+o*4+r]);
        acc[32+o*4+r] = fmaf(in4[r].w, wF.w, acc[32+o*4+r]);
      }
    }
  }
  int cnt = 32;
  #pragma unroll
  for (int s=0; s<6; ++s){
    const bool hib = (lane >> s) & 1;
    #pragma unroll
    for (int a=0; a<32; ++a){
      if (a < cnt){
        float sent = hib ? acc[a] : acc[a+cnt];
        float got = __shfl_xor(sent, 1<<s, 64);
        acc[a] = (hib ? acc[a+cnt] : acc[a]) + got;
      }
    }
    cnt >>= 1;
  }
  __shared__ float red[4][64];
  red[wv][lane] = acc[0];
  __syncthreads();
  if (tid < 64){
    float tot = red[0][tid]+red[1][tid]+red[2][tid]+red[3][tid];
    int a = (int)(__brev((unsigned)tid) >> 26);   // bitrev6
    int f = a >> 5, o = (a>>2)&7, r = a&3;
    int t = t0 + r;
    if (f==0) ig_out[o*S_LEN + t] = tot + igb[o];
    else      lsf_out[o*S_LEN + t] = logsigf(tot + fgb[o]);
  }
}

// ---------------- Kernel B: per-head scans ---------------------------------
__global__ __launch_bounds__(256) void scan_kernel(
    const float* __restrict__ ig, const float* __restrict__ lsf,
    float* __restrict__ cs_out, float* __restrict__ M_out, float* __restrict__ m_out){
  const int h = blockIdx.x;
  const int tid = threadIdx.x;
  __shared__ float tt[256];
  const int base = tid*8;
  const float* src = lsf + h*S_LEN;
  float loc[8]; float tot = 0.f;
  #pragma unroll
  for (int i=0;i<8;++i){ tot += src[base+i]; loc[i]=tot; }
  tt[tid]=tot; __syncthreads();
  for (int off=1; off<256; off<<=1){
    float add = (tid>=off)? tt[tid-off] : 0.f;
    __syncthreads();
    tt[tid] += add;
    __syncthreads();
  }
  const float excl = tt[tid] - tot;
  float csv[8];
  #pragma unroll
  for (int i=0;i<8;++i){ csv[i] = excl + loc[i]; cs_out[h*S_LEN+base+i]=csv[i]; }
  const float* igp = ig + h*S_LEN;
  float mloc[8], mval[8]; float mtot = -INFINITY;
  #pragma unroll
  for (int i=0;i<8;++i){
    float m = igp[base+i] - csv[i];
    mval[i] = m;
    mtot = fmaxf(mtot, m);
    mloc[i] = mtot;
  }
  __syncthreads();
  tt[tid]=mtot; __syncthreads();
  for (int off=1; off<256; off<<=1){
    float add = (tid>=off)? tt[tid-off] : -INFINITY;
    __syncthreads();
    tt[tid] = fmaxf(tt[tid], add);
    __syncthreads();
  }
  const float exclm = (tid>0)? tt[tid-1] : -INFINITY;
  #pragma unroll
  for (int i=0;i<8;++i){
    M_out[h*S_LEN+base+i] = fmaxf(exclm, mloc[i]);
    m_out[h*S_LEN+base+i] = mval[i];
  }
}

// ---------------- Kernel P2: V transpose -> vt[h][d][s] bf16 ---------------
__global__ __launch_bounds__(256) void vtrans(
    const float* __restrict__ v, ushort* __restrict__ vt){
  const int s0 = blockIdx.x*64, d0 = blockIdx.y*64, h = blockIdx.z;
  __shared__ float T[64][65];
  const int r = threadIdx.x>>2, cq = threadIdx.x&3;
  #pragma unroll
  for (int i=0;i<4;++i){
    int col = cq*16 + i*4;
    float4 val = *(const float4*)(v + (size_t)(s0+r)*E_DIM + h*DH + d0 + col);
    T[r][col]=val.x; T[r][col+1]=val.y; T[r][col+2]=val.z; T[r][col+3]=val.w;
  }
  __syncthreads();
  ushort tmp[16];
  #pragma unroll
  for (int i=0;i<16;++i) tmp[i] = f2bf(T[cq*16+i][r]);
  ushort* dst = vt + ((size_t)(h*DH + d0 + r))*S_LEN + s0 + cq*16;
  uint4 o0, o1;
  ushort* p0 = (ushort*)&o0; ushort* p1 = (ushort*)&o1;
  #pragma unroll
  for (int i=0;i<8;++i){ p0[i]=tmp[i]; p1[i]=tmp[8+i]; }
  *(uint4*)dst = o0;
  *(uint4*)(dst+8) = o1;
}

// ---------------- Kernel C: 32x32 MFMA, K/V/m in LDS, P in regs ------------
// Grid (8 heads, 16 q-tiles). Block 256 = 4 waves x 32 q-rows. KVBLK=64,
// K+V^T+m double-buffered in LDS (global_load_lds + both-sides XOR swizzle).
// Swapped QK^T (mfma(K,Q), C: col=q=lane&31, row=s=CROW(reg)+4*hi), P
// redistributed to PV A-frags via shfl_xor(32)+select. Epilogue in-register.
__global__ __launch_bounds__(256) void mlstm_mfma5(
    const ushort* __restrict__ qb, const ushort* __restrict__ kb,
    const ushort* __restrict__ vt,
    const float* __restrict__ csb, const float* __restrict__ Mxb,
    const float* __restrict__ mbb,
    const float* __restrict__ nw, float* __restrict__ out){
  const int h = blockIdx.x, qtb = blockIdx.y;
  const int tid = threadIdx.x, l = tid & 63, w = tid >> 6;
  const int l31 = l & 31, l15 = l & 15, hi = l >> 5;
  __shared__ ushort KB[2][8192];     // [64 s][16 chunk16] chunk c' = c ^ (row&15)
  __shared__ ushort VB[2][8192];     // [128 d][8 chunk16] chunk c' = c ^ ((d>>1)&7)
  __shared__ float  MB[2][64];

  const int hS = h*S_LEN;
  const ushort* kbh = kb + h*DH;
  const ushort* vth = vt + (size_t)h*DH*S_LEN;
  const float*  mh  = mbb + hS;
  const int t0 = qtb*128;
  const int NT = 2*qtb + 2;
  const int tgq = t0 + w*32 + l31;          // this lane's q (QK C col)
  const float Mq = Mxb[hS + tgq];
  const int wqmax = t0 + w*32 + 31;
  const int vxor = (l31 >> 1) & 7;

  // Q B-frags: col=q=l31, k = ks*16 + hi*8 + j
  bf16x8 qf0,qf1,qf2,qf3,qf4,qf5,qf6,qf7;
  { const ushort* qs = qb + (size_t)tgq*E_DIM + h*DH + hi*8;
    qf0 = *(const bf16x8*)(qs+0);   qf1 = *(const bf16x8*)(qs+16);
    qf2 = *(const bf16x8*)(qs+32);  qf3 = *(const bf16x8*)(qs+48);
    qf4 = *(const bf16x8*)(qs+64);  qf5 = *(const bf16x8*)(qs+80);
    qf6 = *(const bf16x8*)(qs+96);  qf7 = *(const bf16x8*)(qs+112); }

  f32x16 a0 = Z16, a1 = Z16, a2 = Z16, a3 = Z16;
  float rsq = 0.f;

#define STAGE(ktn, bi) {                                                     \
    ushort* kd = &KB[bi][0]; ushort* vd = &VB[bi][0];                        \
    _Pragma("unroll")                                                        \
    for (int i_=0;i_<4;++i_){                                                \
      const int L_ = tid + i_*256; const int row_ = L_>>4, pc_ = L_&15;      \
      stage16(kbh + (size_t)((ktn)*64+row_)*E_DIM + ((pc_^(row_&15))<<3),    \
              kd + L_*8); }                                                  \
    _Pragma("unroll")                                                        \
    for (int i_=0;i_<4;++i_){                                                \
      const int L_ = tid + i_*256; const int d_ = L_>>3, pc_ = L_&7;         \
      stage16(vth + (size_t)d_*S_LEN + (ktn)*64 + ((pc_^((d_>>1)&7))<<3),    \
              vd + L_*8); }                                                  \
    if (tid < 16)                                                            \
      stage16((const ushort*)(mh + (ktn)*64) + tid*8,                        \
              (ushort*)&MB[bi][0] + tid*8); }

#define QKS(cc, rowb, ks, qf) {                                              \
    bf16x8 ka_ = *(const bf16x8*)&Kc[(rowb) + ((((ks)*2+hi)^l15)<<3)];       \
    cc = MFMA3216(ka_, qf, cc); }

#define LV(dt, ks) (*(const bf16x8*)&Vc[((dt)*32+l31)*64 + ((((ks)*2+hi)^vxor)<<3)])

#define PVK(f, ks) {                                                         \
    a0 = MFMA3216(f, LV(0,ks), a0); a1 = MFMA3216(f, LV(1,ks), a1);          \
    a2 = MFMA3216(f, LV(2,ks), a2); a3 = MFMA3216(f, LV(3,ks), a3); }

  // P-block: from 16 C-regs (one 32-s subtile) build two PV A-frags.
#define PBLOCK(cc, stile, fE, fO) {                                          \
    const int sb_ = kt*64 + (stile)*32 + 4*hi;                               \
    const f32x4 mA_ = *(const f32x4*)&Mc[(stile)*32 + 4*hi];                 \
    const f32x4 mB_ = *(const f32x4*)&Mc[(stile)*32 + 8 + 4*hi];             \
    const f32x4 mC_ = *(const f32x4*)&Mc[(stile)*32 + 16 + 4*hi];            \
    const f32x4 mD_ = *(const f32x4*)&Mc[(stile)*32 + 24 + 4*hi];            \
    float p0  = (sb_+0    <= tgq) ? cc[0] *__expf(mA_[0]-Mq) : 0.f;          \
    float p1  = (sb_+1    <= tgq) ? cc[1] *__expf(mA_[1]-Mq) : 0.f;          \
    float p2  = (sb_+2    <= tgq) ? cc[2] *__expf(mA_[2]-Mq) : 0.f;          \
    float p3  = (sb_+3    <= tgq) ? cc[3] *__expf(mA_[3]-Mq) : 0.f;          \
    float p4  = (sb_+8    <= tgq) ? cc[4] *__expf(mB_[0]-Mq) : 0.f;          \
    float p5  = (sb_+9    <= tgq) ? cc[5] *__expf(mB_[1]-Mq) : 0.f;          \
    float p6  = (sb_+10   <= tgq) ? cc[6] *__expf(mB_[2]-Mq) : 0.f;          \
    float p7  = (sb_+11   <= tgq) ? cc[7] *__expf(mB_[3]-Mq) : 0.f;          \
    float p8  = (sb_+16   <= tgq) ? cc[8] *__expf(mC_[0]-Mq) : 0.f;          \
    float p9  = (sb_+17   <= tgq) ? cc[9] *__expf(mC_[1]-Mq) : 0.f;          \
    float p10 = (sb_+18   <= tgq) ? cc[10]*__expf(mC_[2]-Mq) : 0.f;          \
    float p11 = (sb_+19   <= tgq) ? cc[11]*__expf(mC_[3]-Mq) : 0.f;          \
    float p12 = (sb_+24   <= tgq) ? cc[12]*__expf(mD_[0]-Mq) : 0.f;          \
    float p13 = (sb_+25   <= tgq) ? cc[13]*__expf(mD_[1]-Mq) : 0.f;          \
    float p14 = (sb_+26   <= tgq) ? cc[14]*__expf(mD_[2]-Mq) : 0.f;          \
    float p15 = (sb_+27   <= tgq) ? cc[15]*__expf(mD_[3]-Mq) : 0.f;          \
    rsq += ((p0+p1)+(p2+p3))+((p4+p5)+(p6+p7))                               \
         + ((p8+p9)+(p10+p11))+((p12+p13)+(p14+p15));                        \
    unsigned A0_=cvtpk(p0,p1),  A1_=cvtpk(p2,p3);                            \
    unsigned B0_=cvtpk(p4,p5),  B1_=cvtpk(p6,p7);                            \
    unsigned C0_=cvtpk(p8,p9),  C1_=cvtpk(p10,p11);                          \
    unsigned D0_=cvtpk(p12,p13),D1_=cvtpk(p14,p15);                          \
    unsigned A0x_=(unsigned)__shfl_xor((int)A0_,32,64);                      \
    unsigned B0x_=(unsigned)__shfl_xor((int)B0_,32,64);                      \
    unsigned A1x_=(unsigned)__shfl_xor((int)A1_,32,64);                      \
    unsigned B1x_=(unsigned)__shfl_xor((int)B1_,32,64);                      \
    unsigned C0x_=(unsigned)__shfl_xor((int)C0_,32,64);                      \
    unsigned D0x_=(unsigned)__shfl_xor((int)D0_,32,64);                      \
    unsigned C1x_=(unsigned)__shfl_xor((int)C1_,32,64);                      \
    unsigned D1x_=(unsigned)__shfl_xor((int)D1_,32,64);                      \
    { unsigned* u_ = (unsigned*)&fE;                                         \
      u_[0] = hi ? B0x_ : A0_;  u_[1] = hi ? B1x_ : A1_;                     \
      u_[2] = hi ? B0_  : A0x_; u_[3] = hi ? B1_  : A1x_; }                  \
    { unsigned* u_ = (unsigned*)&fO;                                         \
      u_[0] = hi ? D0x_ : C0_;  u_[1] = hi ? D1x_ : C1_;                     \
      u_[2] = hi ? D0_  : C0x_; u_[3] = hi ? D1_  : C1x_; } }

  STAGE(0, 0);
  for (int kt=0; kt<NT; ++kt){
    __syncthreads();                       // stage(kt) landed
    if (kt+1 < NT){ STAGE(kt+1, (kt+1)&1); }
    if (kt*64 <= wqmax){
      const ushort* Kc = &KB[kt&1][0];
      const ushort* Vc = &VB[kt&1][0];
      const float*  Mc = &MB[kt&1][0];
      const int rb0 = l31*128, rb1 = (32+l31)*128;
      bf16x8 fr0, fr1, fr2, fr3;
      {
        f32x16 cc = Z16;
        QKS(cc, rb0, 0, qf0); QKS(cc, rb0, 1, qf1);
        QKS(cc, rb0, 2, qf2); QKS(cc, rb0, 3, qf3);
        QKS(cc, rb0, 4, qf4); QKS(cc, rb0, 5, qf5);
        QKS(cc, rb0, 6, qf6); QKS(cc, rb0, 7, qf7);
        PBLOCK(cc, 0, fr0, fr1);
      }
      {
        f32x16 cc = Z16;
        QKS(cc, rb1, 0, qf0); QKS(cc, rb1, 1, qf1);
        QKS(cc, rb1, 2, qf2); QKS(cc, rb1, 3, qf3);
        QKS(cc, rb1, 4, qf4); QKS(cc, rb1, 5, qf5);
        QKS(cc, rb1, 6, qf6); QKS(cc, rb1, 7, qf7);
        PBLOCK(cc, 1, fr2, fr3);
      }
      PVK(fr0, 0); PVK(fr1, 1); PVK(fr2, 2); PVK(fr3, 3);
    }
  }

  // -------- epilogue (in-register, no LDS) --------
  float rst = rsq + __shfl_xor(rsq, 32, 64);
  const float en = __expf(-(csb[hS+tgq] + Mq));
  const float iv = 1.f/(fmaxf(fabsf(rst), en) + 1e-6f);
  const float nw0 = nw[h*DH +  0 + l31];
  const float nw1 = nw[h*DH + 32 + l31];
  const float nw2 = nw[h*DH + 64 + l31];
  const float nw3 = nw[h*DH + 96 + l31];

#define OUTR(r) {                                                            \
    const float ivr = __shfl(iv, CROW(r) + 4*hi, 64);                        \
    float h0 = a0[r]*ivr, h1 = a1[r]*ivr, h2 = a2[r]*ivr, h3 = a3[r]*ivr;    \
    float s1 = (h0+h1)+(h2+h3);                                              \
    float s2 = (h0*h0+h1*h1)+(h2*h2+h3*h3);                                  \
    s1 += __shfl_xor(s1, 1, 64);  s2 += __shfl_xor(s2, 1, 64);               \
    s1 += __shfl_xor(s1, 2, 64);  s2 += __shfl_xor(s2, 2, 64);               \
    s1 += __shfl_xor(s1, 4, 64);  s2 += __shfl_xor(s2, 4, 64);               \
    s1 += __shfl_xor(s1, 8, 64);  s2 += __shfl_xor(s2, 8, 64);               \
    s1 += __shfl_xor(s1, 16, 64); s2 += __shfl_xor(s2, 16, 64);              \
    const float mean = s1*(1.f/128.f);                                       \
    const float var  = s2*(1.f/128.f) - mean*mean;                           \
    const float rstd = rsqrtf(var + 1e-5f);                                  \
    float* orow = out + (size_t)(t0 + w*32 + CROW(r) + 4*hi)*E_DIM           \
                      + h*DH + l31;                                          \
    orow[0]  = (h0-mean)*rstd*nw0;                                           \
    orow[32] = (h1-mean)*rstd*nw1;                                           \
    orow[64] = (h2-mean)*rstd*nw2;                                           \
    orow[96] = (h3-mean)*rstd*nw3; }

  OUTR(0)  OUTR(1)  OUTR(2)  OUTR(3)
  OUTR(4)  OUTR(5)  OUTR(6)  OUTR(7)
  OUTR(8)  OUTR(9)  OUTR(10) OUTR(11)
  OUTR(12) OUTR(13) OUTR(14) OUTR(15)
}

extern "C" void kernel_launch(void* const* d_in, const int* in_sizes, int n_in,
                              void* d_out, int out_size, void* d_ws, size_t ws_size,
                              hipStream_t stream) {
  const float* q   = (const float*)d_in[0];
  const float* k   = (const float*)d_in[1];
  const float* v   = (const float*)d_in[2];
  const float* igw = (const float*)d_in[3];
  const float* igb = (const float*)d_in[4];
  const float* fgw = (const float*)d_in[5];
  const float* fgb = (const float*)d_in[6];
  const float* nw  = (const float*)d_in[7];
  float* outp = (float*)d_out;

  float* ws  = (float*)d_ws;
  float* ig  = ws;                 // NH*S
  float* lsf = ws + 1*NHEAD*S_LEN;
  float* csb = ws + 2*NHEAD*S_LEN;
  float* Mb  = ws + 3*NHEAD*S_LEN;
  float* mbf = ws + 4*NHEAD*S_LEN;
  ushort* qbb = (ushort*)(ws + 5*NHEAD*S_LEN);          // S*E bf16 (scaled)
  ushort* kbb = qbb + (size_t)S_LEN*E_DIM;              // S*E bf16
  ushort* vtb = kbb + (size_t)S_LEN*E_DIM;              // E*S bf16 (per-head V^T)

  gates_qk<<<512, 256, 0, stream>>>(q, k, v, igw, igb, fgw, fgb, ig, lsf, qbb, kbb);
  scan_kernel<<<NHEAD, 256, 0, stream>>>(ig, lsf, csb, Mb, mbf);
  vtrans<<<dim3(S_LEN/64, DH/64, NHEAD), 256, 0, stream>>>(v, vtb);
  mlstm_mfma5<<<dim3(NHEAD, 16), 256, 0, stream>>>(qbb, kbb, vtb, csb, Mb, mbf, nw, outp);
}

// Round 9
// 60.793 us; speedup vs baseline: 2.3112x; 1.6903x over previous
//
#include <hip/hip_runtime.h>
#include <hip/hip_bf16.h>
#include <math.h>

#define S_LEN 2048
#define E_DIM 1024
#define NHEAD 8
#define DH 128
#define E3 3072

typedef short bf16x8 __attribute__((ext_vector_type(8)));
typedef short bf16x4 __attribute__((ext_vector_type(4)));
typedef float f32x4 __attribute__((ext_vector_type(4)));
typedef float f32x16 __attribute__((ext_vector_type(16)));

#define MFMA3216(a,b,c) __builtin_amdgcn_mfma_f32_32x32x16_bf16(a,b,c,0,0,0)
#define Z16 {0.f,0.f,0.f,0.f,0.f,0.f,0.f,0.f,0.f,0.f,0.f,0.f,0.f,0.f,0.f,0.f}
#define CROW(r) (((r)&3) + 8*((r)>>2))

__device__ __forceinline__ unsigned short f2bf(float f){
  union{float f; unsigned u;} x; x.f = f;
  unsigned r = x.u + 0x7FFF + ((x.u>>16)&1);
  return (unsigned short)(r>>16);
}

__device__ __forceinline__ unsigned cvtpk(float lo, float hi){
  unsigned r;
  asm("v_cvt_pk_bf16_f32 %0, %1, %2" : "=v"(r) : "v"(lo), "v"(hi));
  return r;
}

__device__ __forceinline__ float logsigf(float x){
  return fminf(x, 0.f) - log1pf(expf(-fabsf(x)));
}

typedef const __attribute__((address_space(1))) unsigned int* gas1_t;
typedef __attribute__((address_space(3))) unsigned int* las3_t;
__device__ __forceinline__ void stage16(const ushort* g, ushort* l){
  __builtin_amdgcn_global_load_lds((gas1_t)(const void*)g, (las3_t)(void*)l, 16, 0, 0);
}

// ---------------- Kernel A: gates + q/k bf16 conversion (fused) ------------
__global__ __launch_bounds__(256) void gates_qk(
    const float* __restrict__ q, const float* __restrict__ k, const float* __restrict__ v,
    const float* __restrict__ igw, const float* __restrict__ igb,
    const float* __restrict__ fgw, const float* __restrict__ fgb,
    float* __restrict__ ig_out, float* __restrict__ lsf_out,
    ushort* __restrict__ qbo, ushort* __restrict__ kbo){
  const int t0 = blockIdx.x*4;
  const int tid = threadIdx.x;
  const int lane = tid & 63, wv = tid >> 6;
  float acc[64];
  #pragma unroll
  for (int a=0;a<64;++a) acc[a]=0.f;
  const float sc = 0.08838834764831845f;  // 1/sqrt(128)
  #pragma unroll
  for (int step=0; step<3; ++step){
    const float* src = (step==0)? q : ((step==1)? k : v);
    float4 in4[4];
    #pragma unroll
    for (int r=0;r<4;++r) in4[r] = ((const float4*)src)[(size_t)(t0+r)*256 + tid];
    if (step==0){
      #pragma unroll
      for (int r=0;r<4;++r){
        ushort4 o; o.x=f2bf(in4[r].x*sc); o.y=f2bf(in4[r].y*sc);
        o.z=f2bf(in4[r].z*sc); o.w=f2bf(in4[r].w*sc);
        ((ushort4*)qbo)[(size_t)(t0+r)*256 + tid] = o;
      }
    } else if (step==1){
      #pragma unroll
      for (int r=0;r<4;++r){
        ushort4 o; o.x=f2bf(in4[r].x); o.y=f2bf(in4[r].y);
        o.z=f2bf(in4[r].z); o.w=f2bf(in4[r].w);
        ((ushort4*)kbo)[(size_t)(t0+r)*256 + tid] = o;
      }
    }
    const int wj = step*256 + tid;
    #pragma unroll
    for (int o=0;o<8;++o){
      float4 wI = ((const float4*)igw)[o*768 + wj];
      float4 wF = ((const float4*)fgw)[o*768 + wj];
      #pragma unroll
      for (int r=0;r<4;++r){
        acc[o*4+r]    = fmaf(in4[r].x, wI.x, acc[o*4+r]);
        acc[o*4+r]    = fmaf(in4[r].y, wI.y, acc[o*4+r]);
        acc[o*4+r]    = fmaf(in4[r].z, wI.z, acc[o*4+r]);
        acc[o*4+r]    = fmaf(in4[r].w, wI.w, acc[o*4+r]);
        acc[32+o*4+r] = fmaf(in4[r].x, wF.x, acc[32+o*4+r]);
        acc[32+o*4+r] = fmaf(in4[r].y, wF.y, acc[32+o*4+r]);
        acc[32+o*4+r] = fmaf(in4[r].z, wF.z, acc[32+o*4+r]);
        acc[32+o*4+r] = fmaf(in4[r].w, wF.w, acc[32+o*4+r]);
      }
    }
  }
  int cnt = 32;
  #pragma unroll
  for (int s=0; s<6; ++s){
    const bool hib = (lane >> s) & 1;
    #pragma unroll
    for (int a=0; a<32; ++a){
      if (a < cnt){
        float sent = hib ? acc[a] : acc[a+cnt];
        float got = __shfl_xor(sent, 1<<s, 64);
        acc[a] = (hib ? acc[a+cnt] : acc[a]) + got;
      }
    }
    cnt >>= 1;
  }
  __shared__ float red[4][64];
  red[wv][lane] = acc[0];
  __syncthreads();
  if (tid < 64){
    float tot = red[0][tid]+red[1][tid]+red[2][tid]+red[3][tid];
    int a = (int)(__brev((unsigned)tid) >> 26);   // bitrev6
    int f = a >> 5, o = (a>>2)&7, r = a&3;
    int t = t0 + r;
    if (f==0) ig_out[o*S_LEN + t] = tot + igb[o];
    else      lsf_out[o*S_LEN + t] = logsigf(tot + fgb[o]);
  }
}

// ---------------- Kernel B: per-head scans ---------------------------------
__global__ __launch_bounds__(256) void scan_kernel(
    const float* __restrict__ ig, const float* __restrict__ lsf,
    float* __restrict__ cs_out, float* __restrict__ M_out, float* __restrict__ m_out){
  const int h = blockIdx.x;
  const int tid = threadIdx.x;
  __shared__ float tt[256];
  const int base = tid*8;
  const float* src = lsf + h*S_LEN;
  float loc[8]; float tot = 0.f;
  #pragma unroll
  for (int i=0;i<8;++i){ tot += src[base+i]; loc[i]=tot; }
  tt[tid]=tot; __syncthreads();
  for (int off=1; off<256; off<<=1){
    float add = (tid>=off)? tt[tid-off] : 0.f;
    __syncthreads();
    tt[tid] += add;
    __syncthreads();
  }
  const float excl = tt[tid] - tot;
  float csv[8];
  #pragma unroll
  for (int i=0;i<8;++i){ csv[i] = excl + loc[i]; cs_out[h*S_LEN+base+i]=csv[i]; }
  const float* igp = ig + h*S_LEN;
  float mloc[8], mval[8]; float mtot = -INFINITY;
  #pragma unroll
  for (int i=0;i<8;++i){
    float m = igp[base+i] - csv[i];
    mval[i] = m;
    mtot = fmaxf(mtot, m);
    mloc[i] = mtot;
  }
  __syncthreads();
  tt[tid]=mtot; __syncthreads();
  for (int off=1; off<256; off<<=1){
    float add = (tid>=off)? tt[tid-off] : -INFINITY;
    __syncthreads();
    tt[tid] = fmaxf(tt[tid], add);
    __syncthreads();
  }
  const float exclm = (tid>0)? tt[tid-1] : -INFINITY;
  #pragma unroll
  for (int i=0;i<8;++i){
    M_out[h*S_LEN+base+i] = fmaxf(exclm, mloc[i]);
    m_out[h*S_LEN+base+i] = mval[i];
  }
}

// ---------------- Kernel P2: V transpose -> vt[h][d][s] bf16 ---------------
__global__ __launch_bounds__(256) void vtrans(
    const float* __restrict__ v, ushort* __restrict__ vt){
  const int s0 = blockIdx.x*64, d0 = blockIdx.y*64, h = blockIdx.z;
  __shared__ float T[64][65];
  const int r = threadIdx.x>>2, cq = threadIdx.x&3;
  #pragma unroll
  for (int i=0;i<4;++i){
    int col = cq*16 + i*4;
    float4 val = *(const float4*)(v + (size_t)(s0+r)*E_DIM + h*DH + d0 + col);
    T[r][col]=val.x; T[r][col+1]=val.y; T[r][col+2]=val.z; T[r][col+3]=val.w;
  }
  __syncthreads();
  ushort tmp[16];
  #pragma unroll
  for (int i=0;i<16;++i) tmp[i] = f2bf(T[cq*16+i][r]);
  ushort* dst = vt + ((size_t)(h*DH + d0 + r))*S_LEN + s0 + cq*16;
  uint4 o0, o1;
  ushort* p0 = (ushort*)&o0; ushort* p1 = (ushort*)&o1;
  #pragma unroll
  for (int i=0;i<8;++i){ p0[i]=tmp[i]; p1[i]=tmp[8+i]; }
  *(uint4*)dst = o0;
  *(uint4*)(dst+8) = o1;
}

// ---------------- Kernel C: 512-block LPT, 32q tiles, s-split waves --------
// Grid (8 heads, 64 q-tiles, big-first). Block 256 = 4 waves; per 128-s tile
// wave w owns s-quarter w (32 s): 8 QK + 8 PV MFMA, no duplication.
// K[128s][128d] + V^T[128d][128s] single-buffered LDS (global_load_lds +
// both-sides XOR swizzle). P in regs (swapped QK^T + shfl redistribution).
// Epilogue: 4-wave partial-O reduce via LDS union (stride-132) + LN.
__global__ __launch_bounds__(256, 2) void mlstm_mfma6(
    const ushort* __restrict__ qb, const ushort* __restrict__ kb,
    const ushort* __restrict__ vt,
    const float* __restrict__ csb, const float* __restrict__ Mxb,
    const float* __restrict__ mbb,
    const float* __restrict__ nw, float* __restrict__ out){
  const int h = blockIdx.x;
  const int qt = 63 - blockIdx.y;            // LPT: biggest q-tile first
  const int tid = threadIdx.x, l = tid & 63;
  const int sq = tid >> 6;                   // wave = s-quarter 0..3
  const int l31 = l & 31, l15 = l & 15, hi = l >> 5;

  __shared__ __align__(16) float UNI[4*32*132];   // 67584 B union
  __shared__ float MB[128];
  __shared__ float rsL[4][32];
  ushort* Kb = (ushort*)UNI;                 // 32 KB: [128 s][16 chunks]
  ushort* Vb = Kb + 16384;                   // 32 KB: [128 d][16 chunks]
  float*  Part = UNI;                        // [4 w][32 q][132]

  const int hS = h*S_LEN;
  const ushort* kbh = kb + h*DH;
  const ushort* vth = vt + (size_t)h*DH*S_LEN;
  const float*  mh  = mbb + hS;
  const int t0 = qt*32;
  const int NT = (t0 + 31)/128 + 1;
  const int tgq = t0 + l31;
  const float Mq = Mxb[hS + tgq];

  // Q B-frags: col=q=l31, k = ks*16 + hi*8 + j  (identical to r8, verified)
  bf16x8 qf0,qf1,qf2,qf3,qf4,qf5,qf6,qf7;
  { const ushort* qs = qb + (size_t)tgq*E_DIM + h*DH + hi*8;
    qf0 = *(const bf16x8*)(qs+0);   qf1 = *(const bf16x8*)(qs+16);
    qf2 = *(const bf16x8*)(qs+32);  qf3 = *(const bf16x8*)(qs+48);
    qf4 = *(const bf16x8*)(qs+64);  qf5 = *(const bf16x8*)(qs+80);
    qf6 = *(const bf16x8*)(qs+96);  qf7 = *(const bf16x8*)(qs+112); }

  f32x16 a0 = Z16, a1 = Z16, a2 = Z16, a3 = Z16;
  float rsq = 0.f;

#define STAGE6(ktv) {                                                        \
    _Pragma("unroll")                                                        \
    for (int i_=0;i_<8;++i_){                                                \
      const int L_ = tid + i_*256; const int row_ = L_>>4, pc_ = L_&15;      \
      stage16(kbh + (size_t)((ktv)*128+row_)*E_DIM + ((pc_^(row_&15))<<3),   \
              Kb + (size_t)L_*8); }                                          \
    _Pragma("unroll")                                                        \
    for (int i_=0;i_<8;++i_){                                                \
      const int L_ = tid + i_*256; const int d_ = L_>>4, pc_ = L_&15;        \
      stage16(vth + (size_t)d_*S_LEN + (ktv)*128 + ((pc_^(d_&15))<<3),       \
              Vb + (size_t)L_*8); }                                          \
    if (tid < 32)                                                            \
      stage16((const ushort*)(mh + (ktv)*128) + tid*8,                       \
              (ushort*)MB + tid*8); }

#define LV6(dt, cs) (*(const bf16x8*)(Vb + (size_t)((dt)*32+l31)*128 + (((cs)^l15)<<3)))

  for (int kt=0; kt<NT; ++kt){
    if (kt) __syncthreads();                 // prev tile's LDS readers done
    STAGE6(kt);
    __syncthreads();                         // stage landed (vmcnt drained)

    // ---- QK^T: this wave's 32-s quarter x 32 q over d=128 ----
    const ushort* kbase = Kb + (size_t)(sq*32 + l31)*128;
    f32x16 cc = Z16;
    { bf16x8 ka;
      ka = *(const bf16x8*)(kbase + (((0*2+hi)^l15)<<3)); cc = MFMA3216(ka, qf0, cc);
      ka = *(const bf16x8*)(kbase + (((1*2+hi)^l15)<<3)); cc = MFMA3216(ka, qf1, cc);
      ka = *(const bf16x8*)(kbase + (((2*2+hi)^l15)<<3)); cc = MFMA3216(ka, qf2, cc);
      ka = *(const bf16x8*)(kbase + (((3*2+hi)^l15)<<3)); cc = MFMA3216(ka, qf3, cc);
      ka = *(const bf16x8*)(kbase + (((4*2+hi)^l15)<<3)); cc = MFMA3216(ka, qf4, cc);
      ka = *(const bf16x8*)(kbase + (((5*2+hi)^l15)<<3)); cc = MFMA3216(ka, qf5, cc);
      ka = *(const bf16x8*)(kbase + (((6*2+hi)^l15)<<3)); cc = MFMA3216(ka, qf6, cc);
      ka = *(const bf16x8*)(kbase + (((7*2+hi)^l15)<<3)); cc = MFMA3216(ka, qf7, cc); }

    // ---- P block (verified r8 machinery): mask+exp+pack+redistribute ----
    bf16x8 fE, fO;
    {
      const int sb_ = kt*128 + sq*32 + 4*hi;
      const f32x4 mA_ = *(const f32x4*)&MB[sq*32 +  0 + 4*hi];
      const f32x4 mB_ = *(const f32x4*)&MB[sq*32 +  8 + 4*hi];
      const f32x4 mC_ = *(const f32x4*)&MB[sq*32 + 16 + 4*hi];
      const f32x4 mD_ = *(const f32x4*)&MB[sq*32 + 24 + 4*hi];
      float p0  = (sb_+0  <= tgq) ? cc[0] *__expf(mA_[0]-Mq) : 0.f;
      float p1  = (sb_+1  <= tgq) ? cc[1] *__expf(mA_[1]-Mq) : 0.f;
      float p2  = (sb_+2  <= tgq) ? cc[2] *__expf(mA_[2]-Mq) : 0.f;
      float p3  = (sb_+3  <= tgq) ? cc[3] *__expf(mA_[3]-Mq) : 0.f;
      float p4  = (sb_+8  <= tgq) ? cc[4] *__expf(mB_[0]-Mq) : 0.f;
      float p5  = (sb_+9  <= tgq) ? cc[5] *__expf(mB_[1]-Mq) : 0.f;
      float p6  = (sb_+10 <= tgq) ? cc[6] *__expf(mB_[2]-Mq) : 0.f;
      float p7  = (sb_+11 <= tgq) ? cc[7] *__expf(mB_[3]-Mq) : 0.f;
      float p8  = (sb_+16 <= tgq) ? cc[8] *__expf(mC_[0]-Mq) : 0.f;
      float p9  = (sb_+17 <= tgq) ? cc[9] *__expf(mC_[1]-Mq) : 0.f;
      float p10 = (sb_+18 <= tgq) ? cc[10]*__expf(mC_[2]-Mq) : 0.f;
      float p11 = (sb_+19 <= tgq) ? cc[11]*__expf(mC_[3]-Mq) : 0.f;
      float p12 = (sb_+24 <= tgq) ? cc[12]*__expf(mD_[0]-Mq) : 0.f;
      float p13 = (sb_+25 <= tgq) ? cc[13]*__expf(mD_[1]-Mq) : 0.f;
      float p14 = (sb_+26 <= tgq) ? cc[14]*__expf(mD_[2]-Mq) : 0.f;
      float p15 = (sb_+27 <= tgq) ? cc[15]*__expf(mD_[3]-Mq) : 0.f;
      rsq += ((p0+p1)+(p2+p3))+((p4+p5)+(p6+p7))
           + ((p8+p9)+(p10+p11))+((p12+p13)+(p14+p15));
      unsigned A0_=cvtpk(p0,p1),  A1_=cvtpk(p2,p3);
      unsigned B0_=cvtpk(p4,p5),  B1_=cvtpk(p6,p7);
      unsigned C0_=cvtpk(p8,p9),  C1_=cvtpk(p10,p11);
      unsigned D0_=cvtpk(p12,p13),D1_=cvtpk(p14,p15);
      unsigned A0x_=(unsigned)__shfl_xor((int)A0_,32,64);
      unsigned B0x_=(unsigned)__shfl_xor((int)B0_,32,64);
      unsigned A1x_=(unsigned)__shfl_xor((int)A1_,32,64);
      unsigned B1x_=(unsigned)__shfl_xor((int)B1_,32,64);
      unsigned C0x_=(unsigned)__shfl_xor((int)C0_,32,64);
      unsigned D0x_=(unsigned)__shfl_xor((int)D0_,32,64);
      unsigned C1x_=(unsigned)__shfl_xor((int)C1_,32,64);
      unsigned D1x_=(unsigned)__shfl_xor((int)D1_,32,64);
      { unsigned* u_ = (unsigned*)&fE;
        u_[0] = hi ? B0x_ : A0_;  u_[1] = hi ? B1x_ : A1_;
        u_[2] = hi ? B0_  : A0x_; u_[3] = hi ? B1_  : A1x_; }
      { unsigned* u_ = (unsigned*)&fO;
        u_[0] = hi ? D0x_ : C0_;  u_[1] = hi ? D1x_ : C1_;
        u_[2] = hi ? D0_  : C0x_; u_[3] = hi ? D1_  : C1x_; }
    }

    // ---- PV: K=16 per frag, s = sq*32 + ks*16 + hi*8 + j ----
    a0 = MFMA3216(fE, LV6(0, sq*4 + 0 + hi), a0);
    a1 = MFMA3216(fE, LV6(1, sq*4 + 0 + hi), a1);
    a2 = MFMA3216(fE, LV6(2, sq*4 + 0 + hi), a2);
    a3 = MFMA3216(fE, LV6(3, sq*4 + 0 + hi), a3);
    a0 = MFMA3216(fO, LV6(0, sq*4 + 2 + hi), a0);
    a1 = MFMA3216(fO, LV6(1, sq*4 + 2 + hi), a1);
    a2 = MFMA3216(fO, LV6(2, sq*4 + 2 + hi), a2);
    a3 = MFMA3216(fO, LV6(3, sq*4 + 2 + hi), a3);
  }

  // -------- epilogue: cross-wave reduce (LDS union) + normalizer + LN ------
  __syncthreads();                           // all K/V LDS reads done
  #pragma unroll
  for (int r=0;r<16;++r){
    const int qrow = CROW(r) + 4*hi;
    float* pr = Part + (size_t)(sq*32 + qrow)*132 + l31;
    pr[0]  = a0[r];
    pr[32] = a1[r];
    pr[64] = a2[r];
    pr[96] = a3[r];
  }
  rsq += __shfl_xor(rsq, 32, 64);
  if (l < 32) rsL[sq][l31] = rsq;
  __syncthreads();

  {
    const int q = tid >> 3, dg = tid & 7;    // q 0..31, d-group 0..7
    f32x4 os0={0.f,0.f,0.f,0.f}, os1=os0, os2=os0, os3=os0;
    #pragma unroll
    for (int w2=0; w2<4; ++w2){
      const float* pb = Part + (size_t)(w2*32 + q)*132 + dg*16;
      os0 += *(const f32x4*)(pb+0);
      os1 += *(const f32x4*)(pb+4);
      os2 += *(const f32x4*)(pb+8);
      os3 += *(const f32x4*)(pb+12);
    }
    const float rstot = rsL[0][q]+rsL[1][q]+rsL[2][q]+rsL[3][q];
    const int tq = t0 + q;
    const float en = __expf(-(csb[hS+tq] + Mxb[hS+tq]));
    const float iv = 1.f/(fmaxf(fabsf(rstot), en) + 1e-6f);
    f32x4 h0, h1, h2, h3;
    h0[0]=os0[0]*iv; h0[1]=os0[1]*iv; h0[2]=os0[2]*iv; h0[3]=os0[3]*iv;
    h1[0]=os1[0]*iv; h1[1]=os1[1]*iv; h1[2]=os1[2]*iv; h1[3]=os1[3]*iv;
    h2[0]=os2[0]*iv; h2[1]=os2[1]*iv; h2[2]=os2[2]*iv; h2[3]=os2[3]*iv;
    h3[0]=os3[0]*iv; h3[1]=os3[1]*iv; h3[2]=os3[2]*iv; h3[3]=os3[3]*iv;
    float s1 = (h0[0]+h0[1]+h0[2]+h0[3]) + (h1[0]+h1[1]+h1[2]+h1[3])
             + (h2[0]+h2[1]+h2[2]+h2[3]) + (h3[0]+h3[1]+h3[2]+h3[3]);
    float s2 = (h0[0]*h0[0]+h0[1]*h0[1]+h0[2]*h0[2]+h0[3]*h0[3])
             + (h1[0]*h1[0]+h1[1]*h1[1]+h1[2]*h1[2]+h1[3]*h1[3])
             + (h2[0]*h2[0]+h2[1]*h2[1]+h2[2]*h2[2]+h2[3]*h2[3])
             + (h3[0]*h3[0]+h3[1]*h3[1]+h3[2]*h3[2]+h3[3]*h3[3]);
    s1 += __shfl_xor(s1, 1, 64);  s2 += __shfl_xor(s2, 1, 64);
    s1 += __shfl_xor(s1, 2, 64);  s2 += __shfl_xor(s2, 2, 64);
    s1 += __shfl_xor(s1, 4, 64);  s2 += __shfl_xor(s2, 4, 64);
    const float mean = s1*(1.f/128.f);
    const float var  = s2*(1.f/128.f) - mean*mean;
    const float rstd = rsqrtf(var + 1e-5f);
    const float* nb = nw + h*DH + dg*16;
    const f32x4 n0 = *(const f32x4*)(nb+0);
    const f32x4 n1 = *(const f32x4*)(nb+4);
    const f32x4 n2 = *(const f32x4*)(nb+8);
    const f32x4 n3 = *(const f32x4*)(nb+12);
    float* ob = out + (size_t)tq*E_DIM + h*DH + dg*16;
    f32x4 o0v, o1v, o2v, o3v;
    o0v[0]=(h0[0]-mean)*rstd*n0[0]; o0v[1]=(h0[1]-mean)*rstd*n0[1];
    o0v[2]=(h0[2]-mean)*rstd*n0[2]; o0v[3]=(h0[3]-mean)*rstd*n0[3];
    o1v[0]=(h1[0]-mean)*rstd*n1[0]; o1v[1]=(h1[1]-mean)*rstd*n1[1];
    o1v[2]=(h1[2]-mean)*rstd*n1[2]; o1v[3]=(h1[3]-mean)*rstd*n1[3];
    o2v[0]=(h2[0]-mean)*rstd*n2[0]; o2v[1]=(h2[1]-mean)*rstd*n2[1];
    o2v[2]=(h2[2]-mean)*rstd*n2[2]; o2v[3]=(h2[3]-mean)*rstd*n2[3];
    o3v[0]=(h3[0]-mean)*rstd*n3[0]; o3v[1]=(h3[1]-mean)*rstd*n3[1];
    o3v[2]=(h3[2]-mean)*rstd*n3[2]; o3v[3]=(h3[3]-mean)*rstd*n3[3];
    *(f32x4*)(ob+0)  = o0v;
    *(f32x4*)(ob+4)  = o1v;
    *(f32x4*)(ob+8)  = o2v;
    *(f32x4*)(ob+12) = o3v;
  }
}

extern "C" void kernel_launch(void* const* d_in, const int* in_sizes, int n_in,
                              void* d_out, int out_size, void* d_ws, size_t ws_size,
                              hipStream_t stream) {
  const float* q   = (const float*)d_in[0];
  const float* k   = (const float*)d_in[1];
  const float* v   = (const float*)d_in[2];
  const float* igw = (const float*)d_in[3];
  const float* igb = (const float*)d_in[4];
  const float* fgw = (const float*)d_in[5];
  const float* fgb = (const float*)d_in[6];
  const float* nw  = (const float*)d_in[7];
  float* outp = (float*)d_out;

  float* ws  = (float*)d_ws;
  float* ig  = ws;                 // NH*S
  float* lsf = ws + 1*NHEAD*S_LEN;
  float* csb = ws + 2*NHEAD*S_LEN;
  float* Mb  = ws + 3*NHEAD*S_LEN;
  float* mbf = ws + 4*NHEAD*S_LEN;
  ushort* qbb = (ushort*)(ws + 5*NHEAD*S_LEN);          // S*E bf16 (scaled)
  ushort* kbb = qbb + (size_t)S_LEN*E_DIM;              // S*E bf16
  ushort* vtb = kbb + (size_t)S_LEN*E_DIM;              // E*S bf16 (per-head V^T)

  gates_qk<<<512, 256, 0, stream>>>(q, k, v, igw, igb, fgw, fgb, ig, lsf, qbb, kbb);
  scan_kernel<<<NHEAD, 256, 0, stream>>>(ig, lsf, csb, Mb, mbf);
  vtrans<<<dim3(S_LEN/64, DH/64, NHEAD), 256, 0, stream>>>(v, vtb);
  mlstm_mfma6<<<dim3(NHEAD, 64), 256, 0, stream>>>(qbb, kbb, vtb, csb, Mb, mbf, nw, outp);
}